// Round 1
// baseline (135.798 us; speedup 1.0000x reference)
//
#include <hip/hip_runtime.h>
#include <math.h>

#define NMOD 4
#define BB   8
#define NN   4096
#define MM   4608
#define TPB  256
#define TM   768                              // targets per LDS tile (12 KiB as float4)
#define NBLK (NMOD * BB * (NN / TPB))         // 512 partial slots

__global__ __launch_bounds__(TPB) void nn_loss_kernel(
    const float* __restrict__ noisy,   // (B,N,3)
    const float* __restrict__ clean,   // (B,M,3)
    const float* __restrict__ seeds,   // (B,1,3)
    const float* __restrict__ stds,    // (B,)
    const float* __restrict__ disp,    // (NMOD,B,N,3)
    const float* __restrict__ noise,   // (NMOD/2,B,M,3)
    float* __restrict__ partials)      // (NBLK,)
{
    __shared__ float4 tgt[TM];
    __shared__ float red[TPB / 64];

    const int tid = threadIdx.x;
    const int qb  = blockIdx.x * TPB;
    const int b   = blockIdx.y;
    const int mod = blockIdx.z;
    const int n   = qb + tid;

    const float sx = seeds[b * 3 + 0];
    const float sy = seeds[b * 3 + 1];
    const float sz = seeds[b * 3 + 2];

    // query = (noisy - seed) + sum_{j<mod} disp[j]
    float qx = noisy[((size_t)b * NN + n) * 3 + 0] - sx;
    float qy = noisy[((size_t)b * NN + n) * 3 + 1] - sy;
    float qz = noisy[((size_t)b * NN + n) * 3 + 2] - sz;
    for (int j = 0; j < mod; ++j) {
        const size_t o = (((size_t)j * BB + b) * NN + n) * 3;
        qx += disp[o + 0];
        qy += disp[o + 1];
        qz += disp[o + 2];
    }
    const size_t od = (((size_t)mod * BB + b) * NN + n) * 3;
    const float dxp = disp[od + 0];
    const float dyp = disp[od + 1];
    const float dzp = disp[od + 2];

    // noise scale for this module (0 for modules 2,3)
    float nstd = 0.0f;
    if (mod == 0) nstd = stds[b] * 0.25f;      // std/4
    else if (mod == 1) nstd = stds[b] * 0.0625f; // std/16
    const bool noisy_target = (mod < 2);

    const float m2x = -2.0f * qx, m2y = -2.0f * qy, m2z = -2.0f * qz;

    float best  = INFINITY;
    int   bestm = 0;

    for (int mt = 0; mt < MM; mt += TM) {
        __syncthreads();
        // cooperative stage: compute target float4 {x,y,z,||t||^2}
        for (int k = tid; k < TM; k += TPB) {
            const int m = mt + k;
            const size_t oc = ((size_t)b * MM + m) * 3;
            float tx = clean[oc + 0] - sx;
            float ty = clean[oc + 1] - sy;
            float tz = clean[oc + 2] - sz;
            if (noisy_target) {
                const size_t on = (((size_t)mod * BB + b) * MM + m) * 3;
                tx = fmaf(noise[on + 0], nstd, tx);
                ty = fmaf(noise[on + 1], nstd, ty);
                tz = fmaf(noise[on + 2], nstd, tz);
            }
            tgt[k] = make_float4(tx, ty, tz, fmaf(tx, tx, fmaf(ty, ty, tz * tz)));
        }
        __syncthreads();
        // min-scan over staged targets: d2 = ||t||^2 - 2 q.t   (same form as ref)
        #pragma unroll 8
        for (int k = 0; k < TM; ++k) {
            const float4 t = tgt[k];
            const float d2 = fmaf(m2x, t.x, fmaf(m2y, t.y, fmaf(m2z, t.z, t.w)));
            if (d2 < best) { best = d2; bestm = mt + k; }
        }
    }

    // re-derive winning target coordinates
    const size_t oc = ((size_t)b * MM + bestm) * 3;
    float tx = clean[oc + 0] - sx;
    float ty = clean[oc + 1] - sy;
    float tz = clean[oc + 2] - sz;
    if (noisy_target) {
        const size_t on = (((size_t)mod * BB + b) * MM + bestm) * 3;
        tx = fmaf(noise[on + 0], nstd, tx);
        ty = fmaf(noise[on + 1], nstd, ty);
        tz = fmaf(noise[on + 2], nstd, tz);
    }
    // dist = || disp - (t - q) ||^2
    const float ex = dxp - (tx - qx);
    const float ey = dyp - (ty - qy);
    const float ez = dzp - (tz - qz);
    float v = fmaf(ex, ex, fmaf(ey, ey, ez * ez));

    // block reduction (wave shuffle + LDS across 4 waves)
    for (int o = 32; o; o >>= 1) v += __shfl_down(v, o);
    if ((tid & 63) == 0) red[tid >> 6] = v;
    __syncthreads();
    if (tid == 0) {
        const float s = red[0] + red[1] + red[2] + red[3];
        partials[((size_t)blockIdx.z * gridDim.y + blockIdx.y) * gridDim.x + blockIdx.x] = s;
    }
}

__global__ void finalize_kernel(const float* __restrict__ partials, float* __restrict__ out) {
    float s = 0.0f;
    for (int k = threadIdx.x; k < NBLK; k += 64) s += partials[k];
    for (int o = 32; o; o >>= 1) s += __shfl_down(s, o);
    if (threadIdx.x == 0) {
        out[0] = s * (1.0f / BB);
        out[1] = s * (1.0f / BB);
    }
}

extern "C" void kernel_launch(void* const* d_in, const int* in_sizes, int n_in,
                              void* d_out, int out_size, void* d_ws, size_t ws_size,
                              hipStream_t stream) {
    const float* noisy = (const float*)d_in[0];
    const float* clean = (const float*)d_in[1];
    const float* seeds = (const float*)d_in[2];
    const float* stds  = (const float*)d_in[3];
    const float* disp  = (const float*)d_in[4];
    const float* noise = (const float*)d_in[5];
    float* out      = (float*)d_out;
    float* partials = (float*)d_ws;   // NBLK floats = 2 KiB

    dim3 grid(NN / TPB, BB, NMOD);
    nn_loss_kernel<<<grid, TPB, 0, stream>>>(noisy, clean, seeds, stds, disp, noise, partials);
    finalize_kernel<<<1, 64, 0, stream>>>(partials, out);
}

// Round 2
// 103.143 us; speedup vs baseline: 1.3166x; 1.3166x over previous
//
#include <hip/hip_runtime.h>
#include <math.h>

#define NMOD 4
#define BB   8
#define NN   4096
#define MM   4608
#define TPB  256
#define SLICES   4
#define SLICE_M  (MM / SLICES)            // 1152
#define PAIRS    (SLICE_M / 2)            // 576
#define NXBLK    (NN / TPB)               // 16
#define NBLK2    (NMOD * BB * NXBLK)      // 512
#define PACKED_COUNT (NMOD * BB * NN)     // 131072
#define PACKED_BYTES ((size_t)PACKED_COUNT * 8)
#define WS_NEED (PACKED_BYTES + NBLK2 * sizeof(float))

typedef float v2f __attribute__((ext_vector_type(2)));

// ---------------- pass 1: split-M argmin with packed atomicMin combine ------
__global__ __launch_bounds__(TPB, 8) void nn_argmin_kernel(
    const float* __restrict__ noisy, const float* __restrict__ clean,
    const float* __restrict__ seeds, const float* __restrict__ stds,
    const float* __restrict__ disp,  const float* __restrict__ noise,
    unsigned long long* __restrict__ packed_out)
{
    __shared__ float4 txy[PAIRS];   // {x0,x1,y0,y1}
    __shared__ float4 tzw[PAIRS];   // {z0,z1,w0,w1}, w = ||t||^2

    const int tid = threadIdx.x;
    const int b   = blockIdx.y;
    const int mod = blockIdx.z >> 2;
    const int sl  = blockIdx.z & 3;
    const int n   = blockIdx.x * TPB + tid;
    const int mbase = sl * SLICE_M;

    const float sx = seeds[b * 3 + 0];
    const float sy = seeds[b * 3 + 1];
    const float sz = seeds[b * 3 + 2];
    float nstd = 0.0f;
    if (mod == 0) nstd = stds[b] * 0.25f;
    else if (mod == 1) nstd = stds[b] * 0.0625f;
    const bool nt = (mod < 2);

    // stage this slice: 1152 targets -> pair-interleaved SoA
    for (int k = tid; k < SLICE_M; k += TPB) {
        const int m = mbase + k;
        const size_t oc = ((size_t)b * MM + m) * 3;
        float tx = clean[oc + 0] - sx;
        float ty = clean[oc + 1] - sy;
        float tz = clean[oc + 2] - sz;
        if (nt) {
            const size_t on = (((size_t)mod * BB + b) * MM + m) * 3;
            tx = fmaf(noise[on + 0], nstd, tx);
            ty = fmaf(noise[on + 1], nstd, ty);
            tz = fmaf(noise[on + 2], nstd, tz);
        }
        const float tw = fmaf(tx, tx, fmaf(ty, ty, tz * tz));
        float* pxy = (float*)&txy[k >> 1];
        float* pzw = (float*)&tzw[k >> 1];
        const int h = k & 1;
        pxy[0 + h] = tx; pxy[2 + h] = ty;
        pzw[0 + h] = tz; pzw[2 + h] = tw;
    }

    // query = (noisy - seed) + prefix of disp
    float qx = noisy[((size_t)b * NN + n) * 3 + 0] - sx;
    float qy = noisy[((size_t)b * NN + n) * 3 + 1] - sy;
    float qz = noisy[((size_t)b * NN + n) * 3 + 2] - sz;
    for (int j = 0; j < mod; ++j) {
        const size_t o = (((size_t)j * BB + b) * NN + n) * 3;
        qx += disp[o + 0]; qy += disp[o + 1]; qz += disp[o + 2];
    }
    const float q2 = fmaf(qx, qx, fmaf(qy, qy, qz * qz));
    const v2f m2x = {-2.0f * qx, -2.0f * qx};
    const v2f m2y = {-2.0f * qy, -2.0f * qy};
    const v2f m2z = {-2.0f * qz, -2.0f * qz};

    __syncthreads();

    float bestA = INFINITY, bestB = INFINITY;
    int idxA = 0, idxB = 0;
    #pragma unroll 4
    for (int p = 0; p < PAIRS; ++p) {
        const float4 a = txy[p];
        const float4 c = tzw[p];
        const v2f xs = {a.x, a.y};
        const v2f ys = {a.z, a.w};
        const v2f zs = {c.x, c.y};
        const v2f ws = {c.z, c.w};
        const v2f d2 = __builtin_elementwise_fma(m2x, xs,
                        __builtin_elementwise_fma(m2y, ys,
                         __builtin_elementwise_fma(m2z, zs, ws)));
        const bool ca = d2.x < bestA;
        bestA = ca ? d2.x : bestA;
        idxA  = ca ? p    : idxA;
        const bool cb = d2.y < bestB;
        bestB = cb ? d2.y : bestB;
        idxB  = cb ? p    : idxB;
    }

    float best = bestA; int bi = idxA * 2;
    if (bestB < best) { best = bestB; bi = idxB * 2 + 1; }
    const float f = best + q2 + 8.0f;   // strictly positive, order-preserving
    const unsigned long long key =
        ((unsigned long long)__float_as_uint(f) << 32) | (unsigned int)(mbase + bi);
    atomicMin(&packed_out[(((size_t)mod * BB + b) * NN) + n], key);
}

// ---------------- pass 2: unpack winner, compute loss terms ------------------
__global__ __launch_bounds__(TPB) void nn_loss_pass2(
    const float* __restrict__ noisy, const float* __restrict__ clean,
    const float* __restrict__ seeds, const float* __restrict__ stds,
    const float* __restrict__ disp,  const float* __restrict__ noise,
    const unsigned long long* __restrict__ packed_in,
    float* __restrict__ partials)
{
    __shared__ float red[TPB / 64];
    const int tid = threadIdx.x;
    const int b   = blockIdx.y;
    const int mod = blockIdx.z;
    const int n   = blockIdx.x * TPB + tid;

    const float sx = seeds[b * 3 + 0];
    const float sy = seeds[b * 3 + 1];
    const float sz = seeds[b * 3 + 2];
    float nstd = 0.0f;
    if (mod == 0) nstd = stds[b] * 0.25f;
    else if (mod == 1) nstd = stds[b] * 0.0625f;

    float qx = noisy[((size_t)b * NN + n) * 3 + 0] - sx;
    float qy = noisy[((size_t)b * NN + n) * 3 + 1] - sy;
    float qz = noisy[((size_t)b * NN + n) * 3 + 2] - sz;
    for (int j = 0; j < mod; ++j) {
        const size_t o = (((size_t)j * BB + b) * NN + n) * 3;
        qx += disp[o + 0]; qy += disp[o + 1]; qz += disp[o + 2];
    }
    const size_t od = (((size_t)mod * BB + b) * NN + n) * 3;
    const float dxp = disp[od + 0];
    const float dyp = disp[od + 1];
    const float dzp = disp[od + 2];

    const unsigned gidx =
        (unsigned)(packed_in[(((size_t)mod * BB + b) * NN) + n] & 0xFFFFFFFFull);
    const size_t oc = ((size_t)b * MM + gidx) * 3;
    float tx = clean[oc + 0] - sx;
    float ty = clean[oc + 1] - sy;
    float tz = clean[oc + 2] - sz;
    if (mod < 2) {
        const size_t on = (((size_t)mod * BB + b) * MM + gidx) * 3;
        tx = fmaf(noise[on + 0], nstd, tx);
        ty = fmaf(noise[on + 1], nstd, ty);
        tz = fmaf(noise[on + 2], nstd, tz);
    }
    const float ex = dxp - (tx - qx);
    const float ey = dyp - (ty - qy);
    const float ez = dzp - (tz - qz);
    float v = fmaf(ex, ex, fmaf(ey, ey, ez * ez));

    for (int o = 32; o; o >>= 1) v += __shfl_down(v, o);
    if ((tid & 63) == 0) red[tid >> 6] = v;
    __syncthreads();
    if (tid == 0) {
        const float s = red[0] + red[1] + red[2] + red[3];
        partials[(((size_t)mod * BB + b) * NXBLK) + blockIdx.x] = s;
    }
}

__global__ void finalize_kernel(const float* __restrict__ partials, float* __restrict__ out) {
    float s = 0.0f;
    for (int k = threadIdx.x; k < NBLK2; k += 64) s += partials[k];
    for (int o = 32; o; o >>= 1) s += __shfl_down(s, o);
    if (threadIdx.x == 0) {
        out[0] = s * (1.0f / BB);
        out[1] = s * (1.0f / BB);
    }
}

// ---------------- fallback (round-1 monolithic path, needs only 2 KiB ws) ----
#define TM 768
__global__ __launch_bounds__(TPB) void nn_loss_kernel(
    const float* __restrict__ noisy, const float* __restrict__ clean,
    const float* __restrict__ seeds, const float* __restrict__ stds,
    const float* __restrict__ disp,  const float* __restrict__ noise,
    float* __restrict__ partials)
{
    __shared__ float4 tgt[TM];
    __shared__ float red[TPB / 64];
    const int tid = threadIdx.x;
    const int b = blockIdx.y, mod = blockIdx.z;
    const int n = blockIdx.x * TPB + tid;
    const float sx = seeds[b*3+0], sy = seeds[b*3+1], sz = seeds[b*3+2];
    float qx = noisy[((size_t)b*NN+n)*3+0] - sx;
    float qy = noisy[((size_t)b*NN+n)*3+1] - sy;
    float qz = noisy[((size_t)b*NN+n)*3+2] - sz;
    for (int j = 0; j < mod; ++j) {
        const size_t o = (((size_t)j*BB + b)*NN + n)*3;
        qx += disp[o+0]; qy += disp[o+1]; qz += disp[o+2];
    }
    const size_t od = (((size_t)mod*BB + b)*NN + n)*3;
    const float dxp = disp[od+0], dyp = disp[od+1], dzp = disp[od+2];
    float nstd = 0.0f;
    if (mod == 0) nstd = stds[b]*0.25f; else if (mod == 1) nstd = stds[b]*0.0625f;
    const bool nt = (mod < 2);
    const float m2x = -2.0f*qx, m2y = -2.0f*qy, m2z = -2.0f*qz;
    float best = INFINITY; int bestm = 0;
    for (int mt = 0; mt < MM; mt += TM) {
        __syncthreads();
        for (int k = tid; k < TM; k += TPB) {
            const int m = mt + k;
            const size_t oc = ((size_t)b*MM + m)*3;
            float tx = clean[oc+0]-sx, ty = clean[oc+1]-sy, tz = clean[oc+2]-sz;
            if (nt) {
                const size_t on = (((size_t)mod*BB + b)*MM + m)*3;
                tx = fmaf(noise[on+0], nstd, tx);
                ty = fmaf(noise[on+1], nstd, ty);
                tz = fmaf(noise[on+2], nstd, tz);
            }
            tgt[k] = make_float4(tx, ty, tz, fmaf(tx,tx,fmaf(ty,ty,tz*tz)));
        }
        __syncthreads();
        #pragma unroll 8
        for (int k = 0; k < TM; ++k) {
            const float4 t = tgt[k];
            const float d2 = fmaf(m2x, t.x, fmaf(m2y, t.y, fmaf(m2z, t.z, t.w)));
            if (d2 < best) { best = d2; bestm = mt + k; }
        }
    }
    const size_t oc = ((size_t)b*MM + bestm)*3;
    float tx = clean[oc+0]-sx, ty = clean[oc+1]-sy, tz = clean[oc+2]-sz;
    if (nt) {
        const size_t on = (((size_t)mod*BB + b)*MM + bestm)*3;
        tx = fmaf(noise[on+0], nstd, tx);
        ty = fmaf(noise[on+1], nstd, ty);
        tz = fmaf(noise[on+2], nstd, tz);
    }
    const float ex = dxp - (tx - qx), ey = dyp - (ty - qy), ez = dzp - (tz - qz);
    float v = fmaf(ex, ex, fmaf(ey, ey, ez*ez));
    for (int o = 32; o; o >>= 1) v += __shfl_down(v, o);
    if ((tid & 63) == 0) red[tid >> 6] = v;
    __syncthreads();
    if (tid == 0)
        partials[(((size_t)mod*BB + b)*NXBLK) + blockIdx.x] = red[0]+red[1]+red[2]+red[3];
}

extern "C" void kernel_launch(void* const* d_in, const int* in_sizes, int n_in,
                              void* d_out, int out_size, void* d_ws, size_t ws_size,
                              hipStream_t stream) {
    const float* noisy = (const float*)d_in[0];
    const float* clean = (const float*)d_in[1];
    const float* seeds = (const float*)d_in[2];
    const float* stds  = (const float*)d_in[3];
    const float* disp  = (const float*)d_in[4];
    const float* noise = (const float*)d_in[5];
    float* out = (float*)d_out;

    if (ws_size >= WS_NEED) {
        unsigned long long* packed = (unsigned long long*)d_ws;
        float* partials = (float*)((char*)d_ws + PACKED_BYTES);
        hipMemsetAsync(d_ws, 0xFF, PACKED_BYTES, stream);
        dim3 g1(NXBLK, BB, NMOD * SLICES);
        nn_argmin_kernel<<<g1, TPB, 0, stream>>>(noisy, clean, seeds, stds, disp, noise, packed);
        dim3 g2(NXBLK, BB, NMOD);
        nn_loss_pass2<<<g2, TPB, 0, stream>>>(noisy, clean, seeds, stds, disp, noise, packed, partials);
        finalize_kernel<<<1, 64, 0, stream>>>(partials, out);
    } else {
        float* partials = (float*)d_ws;
        dim3 grid(NXBLK, BB, NMOD);
        nn_loss_kernel<<<grid, TPB, 0, stream>>>(noisy, clean, seeds, stds, disp, noise, partials);
        finalize_kernel<<<1, 64, 0, stream>>>(partials, out);
    }
}